// Round 1
// 538.520 us; speedup vs baseline: 1.0927x; 1.0927x over previous
//
#include <hip/hip_runtime.h>

constexpr int SEQ    = 128;
constexpr int NVOCAB = 32000;

// ---------------- workspace layout (float offsets) ----------------
constexpr size_t O_HA = 0;                          // [128][256]
constexpr size_t O_HB = O_HA + (size_t)SEQ*256;     // [128][256]
constexpr size_t O_U  = O_HB + (size_t)SEQ*256;     // [128][512]
constexpr size_t O_DT = O_U  + (size_t)SEQ*512;     // [128][512]
constexpr size_t O_ZS = O_DT + (size_t)SEQ*512;     // [128][512] silu(z)
constexpr size_t O_BC = O_ZS + (size_t)SEQ*512;     // [128][32]
constexpr size_t O_YG = O_BC + (size_t)SEQ*32;      // [128][512]
constexpr size_t O_AH = O_YG + (size_t)SEQ*512;     // [128][256]

__device__ __forceinline__ float wsum(float p) {
    #pragma unroll
    for (int m = 1; m < 64; m <<= 1) p += __shfl_xor(p, m);
    return p;
}
__device__ __forceinline__ float dot4(float4 a, float4 b) {
    return a.x*b.x + a.y*b.y + a.z*b.z + a.w*b.w;
}

// ---------------- register-W mini-GEMM, 16 waves, static double-buffer ----------------
// dest[r][c] = sum_k A[r][k]*Wg[c*KK+k] (+addsrc[r][c]) (+bias[c]), c=0..255.
// Wave wv owns cols wv*16..wv*16+15; lane (cs,tq) owns col wv*16+cs, k-slice tq*8..+7
// of each 32-chunk. W global->register, explicit even/odd buffers (no runtime index).
// A: LDS broadcast float4 reads. 2-level shuffle reduce over tq at the end.
// No internal __syncthreads; caller syncs before reading dest.
template<int MR, int KK>
__device__ __forceinline__ void gemmX(
    const float* __restrict__ Wg, const float* __restrict__ A, int AS,
    float* __restrict__ dest, int DS,
    const float* __restrict__ addsrc, int ASS, const float* __restrict__ bias)
{
    const int lane = threadIdx.x & 63;
    const int wv   = threadIdx.x >> 6;       // 0..15
    const int tq = lane & 3, cs = lane >> 2; // k-quarter, col-in-wave
    const int c  = wv*16 + cs;               // 0..255
    const float* Wp = Wg + (size_t)c*KK + tq*8;
    float acc[MR];
    #pragma unroll
    for (int r = 0; r < MR; ++r) acc[r] = 0.0f;

    float4 w0a = *(const float4*)(Wp);
    float4 w0b = *(const float4*)(Wp + 4);
    float4 w1a, w1b;
    #pragma unroll
    for (int kc = 0; kc < KK; kc += 64) {
        if (kc + 32 < KK) {
            w1a = *(const float4*)(Wp + kc + 32);
            w1b = *(const float4*)(Wp + kc + 36);
        }
        #pragma unroll
        for (int r = 0; r < MR; ++r) {
            float4 a0 = *(const float4*)&A[r*AS + kc + tq*8];
            float4 a1 = *(const float4*)&A[r*AS + kc + tq*8 + 4];
            acc[r] += dot4(a0, w0a) + dot4(a1, w0b);
        }
        if (kc + 64 < KK) {
            w0a = *(const float4*)(Wp + kc + 64);
            w0b = *(const float4*)(Wp + kc + 68);
        }
        if (kc + 32 < KK) {
            #pragma unroll
            for (int r = 0; r < MR; ++r) {
                float4 a0 = *(const float4*)&A[r*AS + kc + 32 + tq*8];
                float4 a1 = *(const float4*)&A[r*AS + kc + 36 + tq*8];
                acc[r] += dot4(a0, w1a) + dot4(a1, w1b);
            }
        }
    }
    #pragma unroll
    for (int r = 0; r < MR; ++r) {
        float v = acc[r];
        v += __shfl_xor(v, 1);
        v += __shfl_xor(v, 2);
        acc[r] = v;
    }
    if (tq == 0) {
        #pragma unroll
        for (int r = 0; r < MR; ++r) {
            float v = acc[r];
            if (bias)   v += bias[c];
            if (addsrc) v += addsrc[r*ASS + c];
            dest[r*DS + c] = v;
        }
    }
}

// LayerNorm of one 256-float row by one wave: dst = (src-mean)*rstd*w + b
__device__ __forceinline__ void ln_row(const float* __restrict__ src, float* __restrict__ dst,
                                       const float* __restrict__ w, const float* __restrict__ b)
{
    int lane = threadIdx.x & 63;
    float4 x = *(const float4*)&src[lane*4];
    float sm = wsum(x.x + x.y + x.z + x.w);
    float mean = sm * (1.0f/256.0f);
    float d0 = x.x-mean, d1 = x.y-mean, d2 = x.z-mean, d3 = x.w-mean;
    float var = wsum(d0*d0 + d1*d1 + d2*d2 + d3*d3) * (1.0f/256.0f);
    float rstd = rsqrtf(var + 1e-5f);
    float4 ww = *(const float4*)&w[lane*4];
    float4 bb = *(const float4*)&b[lane*4];
    float4 o;
    o.x = d0*rstd*ww.x + bb.x;
    o.y = d1*rstd*ww.y + bb.y;
    o.z = d2*rstd*ww.z + bb.z;
    o.w = d3*rstd*ww.w + bb.w;
    *(float4*)&dst[lane*4] = o;
}

// ---------------- rowk: per-row fused layer-boundary kernel (1024 threads) ----------------
// Block r: rebuild h rows r-3..r (KC of layer li-1, redundantly), write h[r];
// then KA of layer li: LN1 + in_proj + conv + silu + x_proj + dt_proj.
__global__ __launch_bounds__(1024) void rowk_kernel(
    const int* __restrict__ x, const float* __restrict__ emb,
    const float* __restrict__ n1w_l, const float* __restrict__ n1b_l,
    const float* __restrict__ n2w_l, const float* __restrict__ n2b_l,
    const float* __restrict__ ipw_l, const float* __restrict__ cw_l, const float* __restrict__ cb_l,
    const float* __restrict__ xpw_l, const float* __restrict__ dpw_l, const float* __restrict__ dpb_l,
    const float* __restrict__ opw_l, const float* __restrict__ aivw_l, const float* __restrict__ aivb_l,
    const float* __restrict__ aow_l, const float* __restrict__ aob_l,
    const float* __restrict__ nfw, const float* __restrict__ nfb,
    const float* __restrict__ hin, float* __restrict__ hout,
    const float* __restrict__ ygv, float* __restrict__ uv, float* __restrict__ dtv,
    float* __restrict__ zsv, float* __restrict__ bcv, float* __restrict__ AH,
    int li)
{
    __shared__ float SM[6336];                  // 24.75 KB
    float* hP  = SM;                            // [4][264] h_prev rows
    float* h1  = SM + 1056;                     // [4][264] h_cur rows
    float* sLN = SM + 2112;                     // [4][264]
    float* sAX = SM + 3168;                     // [4][520] yg / v / u-raw
    float* zR  = SM + 5248;                     // [512]
    float* suR = SM + 5760;                     // [512]
    float* sxR = SM + 6272;                     // [64]

    const int r = blockIdx.x;
    const int tid = threadIdx.x;
    const int lane = tid & 63, wv = tid >> 6;
    int rr[4];
    #pragma unroll
    for (int j = 0; j < 4; ++j) { int v = r - 3 + j; rr[j] = v < 0 ? 0 : v; }

    // ---- h_prev rows r-3..r (one write per thread) ----
    {
        int hr = tid >> 8, hc = tid & 255;
        if (li <= 1) hP[hr*264 + hc] = emb[(size_t)x[rr[hr]]*256 + hc];
        else         hP[hr*264 + hc] = hin[rr[hr]*256 + hc];
    }
    __syncthreads();

    float* hC = hP;
    if (li >= 1) {
        // ---- KC (layer li-1): out_proj + resid ; LN2 ; v ; attn_out + resid ----
        {
            int yr = tid >> 9, yc = tid & 511;
            sAX[yr*520 + yc]     = ygv[rr[yr]*512 + yc];
            sAX[(2+yr)*520 + yc] = ygv[rr[2+yr]*512 + yc];
        }
        __syncthreads();
        gemmX<4,512>(opw_l, sAX, 520, h1, 264, hP, 264, nullptr);    // h1 = hP + out_proj(yg)
        __syncthreads();
        if (wv < 4) ln_row(h1 + wv*264, sLN + wv*264, n2w_l, n2b_l);
        __syncthreads();
        gemmX<4,256>(aivw_l, sLN, 264, sAX, 520, nullptr, 0, aivb_l); // v
        __syncthreads();
        gemmX<4,256>(aow_l, sAX, 520, h1, 264, h1, 264, aob_l);       // h1 += ao(v)+b
        __syncthreads();
        hC = h1;
        if (tid < 256) hout[r*256 + tid] = h1[3*264 + tid];
        if (li == 6) {
            if (tid < 256) {
                float v = h1[3*264 + tid];
                float s = wsum(v);
                float q = wsum(v*v);
                if (lane == 0) { sxR[wv] = s; sxR[8 + wv] = q; }
            }
            __syncthreads();
            if (tid < 256) {
                float v = h1[3*264 + tid];
                float mean = (sxR[0]+sxR[1]+sxR[2]+sxR[3]) * (1.0f/256.0f);
                float var  = (sxR[8]+sxR[9]+sxR[10]+sxR[11]) * (1.0f/256.0f) - mean*mean;
                float rstd = rsqrtf(var + 1e-5f);
                AH[r*256 + tid] = (v - mean)*rstd*nfw[tid] + nfb[tid];
            }
            return;
        }
    }

    // ---- KA (layer li) ----
    if (wv < 4) ln_row(hC + wv*264, sLN + wv*264, n1w_l, n1b_l);
    __syncthreads();
    gemmX<4,256>(ipw_l,                   sLN, 264, sAX,       520, nullptr, 0, nullptr);
    __syncthreads();
    gemmX<4,256>(ipw_l + (size_t)256*256, sLN, 264, sAX + 256, 520, nullptr, 0, nullptr);
    __syncthreads();
    gemmX<1,256>(ipw_l + (size_t)512*256, sLN + 3*264, 264, zR,       512, nullptr, 0, nullptr);
    __syncthreads();
    gemmX<1,256>(ipw_l + (size_t)768*256, sLN + 3*264, 264, zR + 256, 512, nullptr, 0, nullptr);
    __syncthreads();

    // conv + bias + silu -> suR, u[r] ; zs[r] = silu(z)
    if (tid < 512) {
        int d = tid;
        float4 c4 = *(const float4*)&cw_l[d*4];
        float acc = cb_l[d];
        if (r >= 3) acc += sAX[d]        * c4.x;
        if (r >= 2) acc += sAX[520 + d]  * c4.y;
        if (r >= 1) acc += sAX[1040 + d] * c4.z;
        acc += sAX[1560 + d] * c4.w;
        float sg = acc / (1.0f + __expf(-acc));
        suR[d] = sg;
        uv[r*512 + d] = sg;
        float z = zR[d];
        zsv[r*512 + d] = z / (1.0f + __expf(-z));
    }
    __syncthreads();

    // x_proj (48 cols, K=512): 16 waves x 3 cols
    {
        float4 a0 = *(const float4*)&suR[lane*4];
        float4 a1 = *(const float4*)&suR[256 + lane*4];
        float p[3];
        #pragma unroll
        for (int j = 0; j < 3; ++j) {
            int c = wv*3 + j;
            float4 q0 = *(const float4*)&xpw_l[(size_t)c*512 + lane*4];
            float4 q1 = *(const float4*)&xpw_l[(size_t)c*512 + 256 + lane*4];
            p[j] = dot4(a0, q0) + dot4(a1, q1);
        }
        #pragma unroll
        for (int m = 1; m < 64; m <<= 1) {
            #pragma unroll
            for (int j = 0; j < 3; ++j) p[j] += __shfl_xor(p[j], m);
        }
        if (lane == 0) {
            #pragma unroll
            for (int j = 0; j < 3; ++j) sxR[wv*3 + j] = p[j];
        }
    }
    __syncthreads();
    if (tid >= 16 && tid < 48) bcv[r*32 + tid - 16] = sxR[tid];

    // dt_proj + bias + softplus
    if (tid < 512) {
        int d = tid;
        float4 sx0 = *(const float4*)&sxR[0];
        float4 sx1 = *(const float4*)&sxR[4];
        float4 sx2 = *(const float4*)&sxR[8];
        float4 sx3 = *(const float4*)&sxR[12];
        const float4* dp = (const float4*)&dpw_l[(size_t)d*16];
        float acc = dpb_l[d] + dot4(dp[0], sx0) + dot4(dp[1], sx1)
                             + dot4(dp[2], sx2) + dot4(dp[3], sx3);
        dtv[r*512 + d] = fmaxf(acc, 0.0f) + log1pf(__expf(-fabsf(acc)));
    }
}

// ---------------- selective scan + skip + gate: full-LDS preload, sync-free inner loop ----------------
// 64 blocks x 128 threads; block handles 8 channels (d), 16 states (s) each.
// All dt/u/zs/B/C for the block's channels preloaded to LDS (transposed, stride 132),
// then 128 sequential steps with zero __syncthreads (serial chain = 1 fma/step).
__global__ __launch_bounds__(128) void scan_kernel(
    const float* __restrict__ dt, const float* __restrict__ u, const float* __restrict__ zs,
    const float* __restrict__ bcv,
    const float* __restrict__ alog_l, const float* __restrict__ dsk_l,
    float* __restrict__ yg)
{
    __shared__ float sdt[8*132];   // [dl][t]
    __shared__ float su2[8*132];
    __shared__ float sz2[8*132];
    __shared__ float sB [16*132];  // [s][t]
    __shared__ float sC [16*132];
    const int tid = threadIdx.x;          // 0..127
    const int s  = tid & 15;
    const int dl = tid >> 4;              // 0..7
    const int d0 = blockIdx.x * 8;
    const int d  = d0 + dl;

    // ---- preload: thread tid owns time-row t = tid ----
    {
        const int t = tid;
        float4 q0, q1;
        q0 = *(const float4*)&dt[t*512 + d0];
        q1 = *(const float4*)&dt[t*512 + d0 + 4];
        sdt[0*132+t]=q0.x; sdt[1*132+t]=q0.y; sdt[2*132+t]=q0.z; sdt[3*132+t]=q0.w;
        sdt[4*132+t]=q1.x; sdt[5*132+t]=q1.y; sdt[6*132+t]=q1.z; sdt[7*132+t]=q1.w;
        q0 = *(const float4*)&u[t*512 + d0];
        q1 = *(const float4*)&u[t*512 + d0 + 4];
        su2[0*132+t]=q0.x; su2[1*132+t]=q0.y; su2[2*132+t]=q0.z; su2[3*132+t]=q0.w;
        su2[4*132+t]=q1.x; su2[5*132+t]=q1.y; su2[6*132+t]=q1.z; su2[7*132+t]=q1.w;
        q0 = *(const float4*)&zs[t*512 + d0];
        q1 = *(const float4*)&zs[t*512 + d0 + 4];
        sz2[0*132+t]=q0.x; sz2[1*132+t]=q0.y; sz2[2*132+t]=q0.z; sz2[3*132+t]=q0.w;
        sz2[4*132+t]=q1.x; sz2[5*132+t]=q1.y; sz2[6*132+t]=q1.z; sz2[7*132+t]=q1.w;
        float4 b0 = *(const float4*)&bcv[t*32 + 0];
        float4 b1 = *(const float4*)&bcv[t*32 + 4];
        float4 b2 = *(const float4*)&bcv[t*32 + 8];
        float4 b3 = *(const float4*)&bcv[t*32 + 12];
        sB[ 0*132+t]=b0.x; sB[ 1*132+t]=b0.y; sB[ 2*132+t]=b0.z; sB[ 3*132+t]=b0.w;
        sB[ 4*132+t]=b1.x; sB[ 5*132+t]=b1.y; sB[ 6*132+t]=b1.z; sB[ 7*132+t]=b1.w;
        sB[ 8*132+t]=b2.x; sB[ 9*132+t]=b2.y; sB[10*132+t]=b2.z; sB[11*132+t]=b2.w;
        sB[12*132+t]=b3.x; sB[13*132+t]=b3.y; sB[14*132+t]=b3.z; sB[15*132+t]=b3.w;
        float4 c0 = *(const float4*)&bcv[t*32 + 16];
        float4 c1 = *(const float4*)&bcv[t*32 + 20];
        float4 c2 = *(const float4*)&bcv[t*32 + 24];
        float4 c3 = *(const float4*)&bcv[t*32 + 28];
        sC[ 0*132+t]=c0.x; sC[ 1*132+t]=c0.y; sC[ 2*132+t]=c0.z; sC[ 3*132+t]=c0.w;
        sC[ 4*132+t]=c1.x; sC[ 5*132+t]=c1.y; sC[ 6*132+t]=c1.z; sC[ 7*132+t]=c1.w;
        sC[ 8*132+t]=c2.x; sC[ 9*132+t]=c2.y; sC[10*132+t]=c2.z; sC[11*132+t]=c2.w;
        sC[12*132+t]=c3.x; sC[13*132+t]=c3.y; sC[14*132+t]=c3.z; sC[15*132+t]=c3.w;
    }
    __syncthreads();

    const float a_ds = -__expf(alog_l[d*16 + s]);
    const float dskv = dsk_l[d];
    float hst = 0.0f;
    #pragma unroll 8
    for (int t = 0; t < SEQ; ++t) {
        float dtvv = sdt[dl*132 + t];
        float uvv  = su2[dl*132 + t];
        hst = __expf(dtvv * a_ds) * hst + dtvv * uvv * sB[s*132 + t];
        float p = hst * sC[s*132 + t];
        p += __shfl_xor(p, 1);
        p += __shfl_xor(p, 2);
        p += __shfl_xor(p, 4);
        p += __shfl_xor(p, 8);
        if (s == 0) yg[t*512 + d] = (p + uvv * dskv) * sz2[dl*132 + t];
    }
}

// ---------------- head GEMM: out(128,32000) = AH @ emb^T + hb ----------------
// 500 blocks x 256 threads, tile 128 rows x 64 vocab cols, per-thread 8x4 acc.
// Register double-buffered global->LDS staging (issue loads before compute phase).
__global__ __launch_bounds__(256) void head_kernel(
    const float* __restrict__ AH, const float* __restrict__ emb,
    const float* __restrict__ hb, float* __restrict__ out)
{
    __shared__ float sA[32*132];   // [k][row], 132-pad: 16B-aligned rows, conflict-free reads
    __shared__ float sW[32*68];    // [k][col]
    const int tid = threadIdx.x;
    const int c0  = blockIdx.x * 64;
    // A staging: thread -> (row, k-half)
    const int ar = tid >> 1;             // 0..127
    const int ak = (tid & 1) * 16;       // 0 / 16
    // W staging: thread -> (col, k-eighth)
    const int wc = tid & 63;             // 0..63
    const int wk = (tid >> 6) * 8;       // 0,8,16,24
    // compute mapping
    const int rg = tid >> 4;             // 0..15 -> rows rg*8..+7
    const int cg = tid & 15;             // 0..15 -> cols cg*4..+3

    const float* Ap = AH  + (size_t)ar*256 + ak;
    const float* Wp = emb + (size_t)(c0 + wc)*256 + wk;

    float4 ra0 = *(const float4*)(Ap + 0);
    float4 ra1 = *(const float4*)(Ap + 4);
    float4 ra2 = *(const float4*)(Ap + 8);
    float4 ra3 = *(const float4*)(Ap + 12);
    float4 rw0 = *(const float4*)(Wp + 0);
    float4 rw1 = *(const float4*)(Wp + 4);

    float acc[8][4] = {};

    for (int kc = 0; kc < 256; kc += 32) {
        if (kc) __syncthreads();
        // write staged regs -> LDS (transposed scatter, <=2-way banks)
        sA[(ak+ 0)*132+ar]=ra0.x; sA[(ak+ 1)*132+ar]=ra0.y; sA[(ak+ 2)*132+ar]=ra0.z; sA[(ak+ 3)*132+ar]=ra0.w;
        sA[(ak+ 4)*132+ar]=ra1.x; sA[(ak+ 5)*132+ar]=ra1.y; sA[(ak+ 6)*132+ar]=ra1.z; sA[(ak+ 7)*132+ar]=ra1.w;
        sA[(ak+ 8)*132+ar]=ra2.x; sA[(ak+ 9)*132+ar]=ra2.y; sA[(ak+10)*132+ar]=ra2.z; sA[(ak+11)*132+ar]=ra2.w;
        sA[(ak+12)*132+ar]=ra3.x; sA[(ak+13)*132+ar]=ra3.y; sA[(ak+14)*132+ar]=ra3.z; sA[(ak+15)*132+ar]=ra3.w;
        sW[(wk+0)*68+wc]=rw0.x; sW[(wk+1)*68+wc]=rw0.y; sW[(wk+2)*68+wc]=rw0.z; sW[(wk+3)*68+wc]=rw0.w;
        sW[(wk+4)*68+wc]=rw1.x; sW[(wk+5)*68+wc]=rw1.y; sW[(wk+6)*68+wc]=rw1.z; sW[(wk+7)*68+wc]=rw1.w;
        __syncthreads();
        // prefetch next chunk (latency hides under the 32-k compute below)
        if (kc + 32 < 256) {
            ra0 = *(const float4*)(Ap + kc + 32);
            ra1 = *(const float4*)(Ap + kc + 36);
            ra2 = *(const float4*)(Ap + kc + 40);
            ra3 = *(const float4*)(Ap + kc + 44);
            rw0 = *(const float4*)(Wp + kc + 32);
            rw1 = *(const float4*)(Wp + kc + 36);
        }
        #pragma unroll
        for (int k = 0; k < 32; ++k) {
            float4 a0 = *(const float4*)&sA[k*132 + rg*8];
            float4 a1 = *(const float4*)&sA[k*132 + rg*8 + 4];
            float4 b  = *(const float4*)&sW[k*68  + cg*4];
            float av[8] = {a0.x,a0.y,a0.z,a0.w, a1.x,a1.y,a1.z,a1.w};
            #pragma unroll
            for (int i = 0; i < 8; ++i) {
                acc[i][0] += av[i]*b.x;
                acc[i][1] += av[i]*b.y;
                acc[i][2] += av[i]*b.z;
                acc[i][3] += av[i]*b.w;
            }
        }
    }

    const int c = c0 + cg*4;
    float4 h4 = *(const float4*)&hb[c];
    #pragma unroll
    for (int i = 0; i < 8; ++i) {
        int r = rg*8 + i;
        float4 o;
        o.x = acc[i][0] + h4.x;
        o.y = acc[i][1] + h4.y;
        o.z = acc[i][2] + h4.z;
        o.w = acc[i][3] + h4.w;
        *(float4*)&out[(size_t)r*NVOCAB + c] = o;
    }
}

// ---------------- launch (14 nodes) ----------------
extern "C" void kernel_launch(void* const* d_in, const int* in_sizes, int n_in,
                              void* d_out, int out_size, void* d_ws, size_t ws_size,
                              hipStream_t stream)
{
    const int*   xin = (const int*)d_in[0];
    const float* emb = (const float*)d_in[1];
    const float* n1w = (const float*)d_in[2];
    const float* n1b = (const float*)d_in[3];
    const float* n2w = (const float*)d_in[4];
    const float* n2b = (const float*)d_in[5];
    const float* ipw = (const float*)d_in[6];
    const float* cw  = (const float*)d_in[7];
    const float* cb  = (const float*)d_in[8];
    const float* xpw = (const float*)d_in[9];
    const float* dpw = (const float*)d_in[10];
    const float* dpb = (const float*)d_in[11];
    const float* alog= (const float*)d_in[12];
    const float* dsk = (const float*)d_in[13];
    const float* opw = (const float*)d_in[14];
    const float* aiw = (const float*)d_in[15];
    const float* aib = (const float*)d_in[16];
    const float* aow = (const float*)d_in[17];
    const float* aob = (const float*)d_in[18];
    const float* nfw = (const float*)d_in[19];
    const float* nfb = (const float*)d_in[20];
    const float* hb  = (const float*)d_in[21];
    float* ws  = (float*)d_ws;
    float* out = (float*)d_out;

    for (int i = 0; i <= 6; ++i) {
        int ka = i <= 5 ? i : 5;          // KA layer (unused when i==6)
        int kc = i >= 1 ? i - 1 : 0;      // KC layer (unused when i==0)
        const float* hin  = (i % 2 == 0) ? ws + O_HA : ws + O_HB;
        float*       hout = (i % 2 == 0) ? ws + O_HB : ws + O_HA;
        rowk_kernel<<<128, 1024, 0, stream>>>(
            xin, emb,
            n1w + ka*256, n1b + ka*256,
            n2w + kc*256, n2b + kc*256,
            ipw + (size_t)ka*1024*256, cw + (size_t)ka*512*4, cb + ka*512,
            xpw + (size_t)ka*48*512, dpw + (size_t)ka*512*16, dpb + ka*512,
            opw + (size_t)kc*256*512,
            aiw + (size_t)kc*768*256 + (size_t)512*256, aib + kc*768 + 512,
            aow + (size_t)kc*256*256, aob + kc*256,
            nfw, nfb,
            hin, hout,
            ws + O_YG, ws + O_U, ws + O_DT, ws + O_ZS, ws + O_BC, ws + O_AH,
            i);
        if (i <= 5)
            scan_kernel<<<64, 128, 0, stream>>>(
                ws + O_DT, ws + O_U, ws + O_ZS, ws + O_BC,
                alog + (size_t)i*512*16, dsk + i*512, ws + O_YG);
    }
    head_kernel<<<NVOCAB/64, 256, 0, stream>>>(ws + O_AH, emb, hb, out);
}